// Round 12
// baseline (217.763 us; speedup 1.0000x reference)
//
#include <hip/hip_runtime.h>
#include <hip/hip_fp16.h>

#define F_IN 128
#define HID  64
#define CAP  96      // max edges per dst node (degrees ~Poisson(16), max ~45)
#define CSHIFT 9     // coarse bucket = dst >> 9 (512 nodes per bucket)
#define CNODES 512
#define NC_MAX 256   // >= ceil(N/512)
#define CCHUNK 4096  // edges per coarse-bin block
#define BCAPC 8960   // entries per coarse bucket (mean 8192, +8.5 sigma)

// ---------------- Pass A: coarse bin (196 buckets), direct global scatter ----------------
__launch_bounds__(256)
__global__ void k_coarse(const int* __restrict__ src, const int* __restrict__ dst,
                         int* __restrict__ acur, int* __restrict__ ent, int E, int nc) {
    __shared__ int s_cnt[NC_MAX];
    __shared__ int s_gb[NC_MAX];
    __shared__ int s_bump[NC_MAX];
    int t = threadIdx.x;
    int e0 = blockIdx.x * CCHUNK;
    int n = E - e0; if (n > CCHUNK) n = CCHUNK;

    for (int i = t; i < nc; i += 256) { s_cnt[i] = 0; s_bump[i] = 0; }
    __syncthreads();
    for (int i = t; i < n; i += 256)
        atomicAdd(&s_cnt[dst[e0 + i] >> CSHIFT], 1);
    __syncthreads();
    if (t < nc) {
        int c = s_cnt[t];
        s_gb[t] = (c > 0) ? atomicAdd(&acur[t], c) : 0;
    }
    __syncthreads();
    for (int i = t; i < n; i += 256) {
        int d = dst[e0 + i], s = src[e0 + i];
        int b = d >> CSHIFT;
        int p = s_gb[b] + atomicAdd(&s_bump[b], 1);
        if (p < BCAPC) ent[(size_t)b * BCAPC + p] = (s << CSHIFT) | (d & (CNODES - 1));
    }
}

// ---------------- Pass B: per-coarse-bucket regroup, 2 blocks per bucket (node halves) ----------------
// Each block scans the bucket's full entry list but only processes its 256-node half:
// no cross-block cursor sharing, csrc windows disjoint. 392 blocks.
__launch_bounds__(512)
__global__ void k_fillc(const int* __restrict__ acur, const int* __restrict__ ent,
                        int* __restrict__ counts, int* __restrict__ csrc, int N) {
    __shared__ int lcnt[256];
    int blk = blockIdx.x, t = threadIdx.x;
    int b = blk >> 1, hf = blk & 1;
    if (t < 256) lcnt[t] = 0;
    __syncthreads();
    int base = b * CNODES + hf * 256;       // first node of my half
    int lo = hf * 256;
    int cnt = acur[b]; if (cnt > BCAPC) cnt = BCAPC;
    const int* ep = ent + (size_t)b * BCAPC;
    for (int i = t; i < cnt; i += 512) {
        int v = ep[i];
        int ld = (v & (CNODES - 1)) - lo;
        if ((unsigned)ld < 256u) {
            int s = v >> CSHIFT;
            int p = atomicAdd(&lcnt[ld], 1);
            if (p < CAP) csrc[(size_t)(base + ld) * CAP + p] = s;
        }
    }
    __syncthreads();
    if (t < 256 && base + t < N) {
        int cc = lcnt[t]; if (cc > CAP) cc = CAP;
        counts[base + t] = cc;
    }
}

// ---------------- GEMM: hn = fp16( (x @ W1) * dinv(row) ) ----------------
#define SX 65
__launch_bounds__(256, 4)
__global__ void k_gemm(const float* __restrict__ x, const float* __restrict__ W1,
                       const int* __restrict__ counts, __half* __restrict__ hn, int N) {
    __shared__ float xT[F_IN * SX];  // 33.3 KB
    int t = threadIdx.x;
    int r0 = blockIdx.x * 64;

    const float4* xg = (const float4*)(x + (size_t)r0 * F_IN);
    int maxf = (N - r0) * (F_IN / 4);
#pragma unroll
    for (int j = 0; j < 8; ++j) {
        int f = t + j * 256;
        int row = f >> 5;
        int k0  = (f & 31) * 4;
        float4 v = (f < maxf) ? xg[f] : make_float4(0.f, 0.f, 0.f, 0.f);
        xT[(k0 + 0) * SX + row] = v.x;
        xT[(k0 + 1) * SX + row] = v.y;
        xT[(k0 + 2) * SX + row] = v.z;
        xT[(k0 + 3) * SX + row] = v.w;
    }
    __syncthreads();

    int lane = t & 63;
    int c0 = __builtin_amdgcn_readfirstlane(t >> 6) * 16;
    int row = r0 + lane;

    float acc[16];
#pragma unroll
    for (int c = 0; c < 16; ++c) acc[c] = 0.f;

    for (int k = 0; k < F_IN; k += 4) {
        float x0 = xT[(k + 0) * SX + lane];
        float x1 = xT[(k + 1) * SX + lane];
        float x2 = xT[(k + 2) * SX + lane];
        float x3 = xT[(k + 3) * SX + lane];
        const float* wr = W1 + (size_t)k * HID + c0;   // scalar address -> s_load
#pragma unroll
        for (int c = 0; c < 16; ++c) {
            float a = acc[c];
            a = fmaf(x0, wr[c], a);
            a = fmaf(x1, wr[HID + c], a);
            a = fmaf(x2, wr[2 * HID + c], a);
            a = fmaf(x3, wr[3 * HID + c], a);
            acc[c] = a;
        }
    }

    if (row < N) {
        float di = rsqrtf((float)(counts[row] + 1));
        __half* hp = hn + (size_t)row * HID + c0;
        unsigned int us[8];
#pragma unroll
        for (int c = 0; c < 16; c += 2) {
            __half2 h2 = __floats2half2_rn(acc[c] * di, acc[c + 1] * di);
            us[c >> 1] = *(unsigned int*)&h2;
        }
        *(uint4*)&hp[0] = make_uint4(us[0], us[1], us[2], us[3]);
        *(uint4*)&hp[8] = make_uint4(us[4], us[5], us[6], us[7]);
    }
}

__device__ inline float4 ldh4(const __half* p) {
    int2 raw = *(const int2*)p;
    __half2 a = *(__half2*)&raw.x, b = *(__half2*)&raw.y;
    float2 fa = __half22float2(a), fb = __half22float2(b);
    return make_float4(fa.x, fa.y, fb.x, fb.y);
}

// ---------------- layer 1 gather (fp16 rows) + self-loop + bias + ReLU + @W2 ----------------
// Round-9 passing version, byte-identical: per-iteration csrc loads (NO shfl idx broadcast —
// that idiom failed correctness twice in rounds 10/11).
__launch_bounds__(256)
__global__ void k_gather1(const int* __restrict__ csrc, const int* __restrict__ counts,
                          const __half* __restrict__ hn, const float* __restrict__ b1,
                          const float* __restrict__ W2, float* __restrict__ zn, int N) {
    int lane = threadIdx.x & 63;
    int r = blockIdx.x * 4 + (threadIdx.x >> 6);
    if (r >= N) return;
    int g  = lane >> 4;
    int li = lane & 15;
    size_t beg = (size_t)r * CAP;
    int cnt = counts[r];

    float4 a0 = make_float4(0.f, 0.f, 0.f, 0.f);
    float4 a1 = make_float4(0.f, 0.f, 0.f, 0.f);
    int j = g;
    for (; j + 4 < cnt; j += 8) {
        int s0 = csrc[beg + j];
        int s1 = csrc[beg + j + 4];
        float4 h0 = ldh4(&hn[(size_t)s0 * HID + li * 4]);
        float4 h1 = ldh4(&hn[(size_t)s1 * HID + li * 4]);
        a0.x += h0.x; a0.y += h0.y; a0.z += h0.z; a0.w += h0.w;
        a1.x += h1.x; a1.y += h1.y; a1.z += h1.z; a1.w += h1.w;
    }
    if (j < cnt) {
        int s0 = csrc[beg + j];
        float4 h0 = ldh4(&hn[(size_t)s0 * HID + li * 4]);
        a0.x += h0.x; a0.y += h0.y; a0.z += h0.z; a0.w += h0.w;
    }
    a0.x += a1.x; a0.y += a1.y; a0.z += a1.z; a0.w += a1.w;

    a0.x += __shfl_xor(a0.x, 16, 64); a0.y += __shfl_xor(a0.y, 16, 64);
    a0.z += __shfl_xor(a0.z, 16, 64); a0.w += __shfl_xor(a0.w, 16, 64);
    a0.x += __shfl_xor(a0.x, 32, 64); a0.y += __shfl_xor(a0.y, 32, 64);
    a0.z += __shfl_xor(a0.z, 32, 64); a0.w += __shfl_xor(a0.w, 32, 64);

    float di = rsqrtf((float)(cnt + 1));
    float4 hr = ldh4(&hn[(size_t)r * HID + li * 4]);
    float4 bv = *(const float4*)&b1[li * 4];
    float4 wv = *(const float4*)&W2[li * 4];
    float vx = fmaxf(di * (a0.x + hr.x) + bv.x, 0.f);
    float vy = fmaxf(di * (a0.y + hr.y) + bv.y, 0.f);
    float vz = fmaxf(di * (a0.z + hr.z) + bv.z, 0.f);
    float vw = fmaxf(di * (a0.w + hr.w) + bv.w, 0.f);
    float p = vx * wv.x + vy * wv.y + vz * wv.z + vw * wv.w;
    p += __shfl_xor(p, 1, 64);
    p += __shfl_xor(p, 2, 64);
    p += __shfl_xor(p, 4, 64);
    p += __shfl_xor(p, 8, 64);
    if (lane == 0) zn[r] = p * di;
}

// ---------------- layer 2 gather: 16 lanes per node ----------------
__global__ void k_gather2(const int* __restrict__ csrc, const int* __restrict__ counts,
                          const float* __restrict__ zn, const float* __restrict__ b2,
                          float* __restrict__ out, int N) {
    int t = blockIdx.x * blockDim.x + threadIdx.x;
    int r = t >> 4, li = t & 15;
    if (r >= N) return;
    size_t beg = (size_t)r * CAP;
    int cnt = counts[r];
    float acc = 0.f;
    for (int j = li; j < cnt; j += 16) {
        acc += zn[csrc[beg + j]];
    }
    acc += __shfl_xor(acc, 1, 64);
    acc += __shfl_xor(acc, 2, 64);
    acc += __shfl_xor(acc, 4, 64);
    acc += __shfl_xor(acc, 8, 64);
    if (li == 0) {
        float di = rsqrtf((float)(cnt + 1));
        out[r] = di * (acc + zn[r]) + b2[0];
    }
}

extern "C" void kernel_launch(void* const* d_in, const int* in_sizes, int n_in,
                              void* d_out, int out_size, void* d_ws, size_t ws_size,
                              hipStream_t stream) {
    const float* x  = (const float*)d_in[0];
    const int*   ei = (const int*)d_in[1];   // [2, E] int32
    const float* W1 = (const float*)d_in[2];
    const float* b1 = (const float*)d_in[3];
    const float* W2 = (const float*)d_in[4];
    const float* b2 = (const float*)d_in[5];
    float* out = (float*)d_out;

    const int N = in_sizes[0] / F_IN;     // 100000
    const int E = in_sizes[1] / 2;        // 1600000
    const int* src = ei;
    const int* dst = ei + E;

    const int nc = (N + CNODES - 1) / CNODES;   // 196 coarse buckets
    const int NBKT = (N + 63) / 64;             // 1563 gemm blocks

    // workspace layout (all 256B-aligned)
    char* ws = (char*)d_ws;
    size_t off = 0;
    auto alloc = [&](size_t bytes) { void* p = ws + off; off += (bytes + 255) & ~255ULL; return p; };
    int*    acur   = (int*)   alloc((size_t)nc * 4);
    int*    counts = (int*)   alloc((size_t)N * 4);
    float*  zn     = (float*) alloc((size_t)N * 4);
    int*    ent    = (int*)   alloc((size_t)nc * BCAPC * 4);  // 7.0 MB
    __half* hn     = (__half*)alloc((size_t)N * HID * 2);     // 12.8 MB
    int*    csrc   = (int*)   alloc((size_t)N * CAP * 4);     // 38.4 MB

    hipMemsetAsync(acur, 0, (size_t)nc * 4, stream);

    const int coarseBlks = (E + CCHUNK - 1) / CCHUNK;   // 391
    k_coarse<<<coarseBlks, 256, 0, stream>>>(src, dst, acur, ent, E, nc);
    k_fillc<<<nc * 2, 512, 0, stream>>>(acur, ent, counts, csrc, N);
    k_gemm<<<NBKT, 256, 0, stream>>>(x, W1, counts, hn, N);
    k_gather1<<<(N + 3) / 4, 256, 0, stream>>>(csrc, counts, hn, b1, W2, zn, N);
    k_gather2<<<((size_t)N * 16 + 255) / 256, 256, 0, stream>>>(csrc, counts, zn, b2, out, N);
}